// Round 2
// baseline (330.742 us; speedup 1.0000x reference)
//
#include <hip/hip_runtime.h>
#include <math.h>

#define SAMPLE_THRESH 0.05f

// Native 4-float vector for nontemporal stores (HIP's float4 is a class type
// that __builtin_nontemporal_store rejects; this ext_vector is bit-identical).
typedef float nfloat4 __attribute__((ext_vector_type(4)));

// Bit-exact squared distance: explicit *_rn intrinsics are contraction
// barriers, so every kernel computes the identical fp32 bit pattern.
// The mask tests exact equality (D == row_min) & (D == col_min).
__device__ __forceinline__ float d2_exact(float xa0, float xa1, float a2,
                                          float xb0, float xb1, float b2) {
    float p  = __fmul_rn(xa1, xb1);
    float q  = __fmaf_rn(xa0, xb0, p);      // dot(xa, xb)
    float s  = __fadd_rn(a2, b2);
    return __fmaf_rn(-2.0f, q, s);          // a2 + b2 - 2*dot
}

// Correctly-rounded sqrt is monotone, so min_j D_j == D_from_d2(min_j d2_j)
// bit-exactly. This lets the min loops skip sqrt entirely.
__device__ __forceinline__ float D_from_d2(float d2) {
    return __fsqrt_rn(fmaxf(d2, 1e-12f));
}

// Kernel A: grid_sample (bilinear, zeros, align_corners=False) of the flow
// channels (warp[...,2], warp[...,3]) and certainty at x_A.
// Apack[i] = (fx, fy, a2, cert);  Bpack[j] = (bx, by, b2, 0)
__global__ __launch_bounds__(256) void sample_kernel(
    const float* __restrict__ xA, const float* __restrict__ xB,
    const float4* __restrict__ warp, const float* __restrict__ cert,
    float4* __restrict__ Apack, float4* __restrict__ Bpack,
    int nA, int nB, int H, int W) {
    int i = blockIdx.x * blockDim.x + threadIdx.x;
    if (i < nA) {
        float px = xA[2 * i + 0], py = xA[2 * i + 1];
        float xf = (px + 1.0f) * (0.5f * (float)W) - 0.5f;
        float yf = (py + 1.0f) * (0.5f * (float)H) - 0.5f;
        float x0f = floorf(xf), y0f = floorf(yf);
        float wx1 = xf - x0f, wy1 = yf - y0f;
        float wx0 = 1.0f - wx1, wy0 = 1.0f - wy1;
        int x0 = (int)x0f, y0 = (int)y0f;
        float fx = 0.0f, fy = 0.0f, cv = 0.0f;
#pragma unroll
        for (int dy = 0; dy < 2; ++dy) {
#pragma unroll
            for (int dx = 0; dx < 2; ++dx) {
                int xi = x0 + dx, yi = y0 + dy;
                float vm = (xi >= 0 && xi < W && yi >= 0 && yi < H) ? 1.0f : 0.0f;
                int xc = min(max(xi, 0), W - 1);
                int yc = min(max(yi, 0), H - 1);
                int idx = yc * W + xc;
                float4 wv = warp[idx];
                float  c  = cert[idx];
                float wgt = (dx ? wx1 : wx0) * (dy ? wy1 : wy0);
                fx += (wv.z * vm) * wgt;
                fy += (wv.w * vm) * wgt;
                cv += (c    * vm) * wgt;
            }
        }
        float a2 = fx * fx + fy * fy;
        Apack[i] = make_float4(fx, fy, a2, cv);
    }
    if (i < nB) {
        float b0 = xB[2 * i + 0], b1 = xB[2 * i + 1];
        Bpack[i] = make_float4(b0, b1, b0 * b0 + b1 * b1, 0.0f);
    }
}

// Fused row-min + col-min over d2 (sqrt hoisted out of the loop).
// 8 rows (cols) per wave: halves the pack-stream L2 traffic vs 4/wave
// (each 16B Bpack load now feeds 8 independent d2+min chains = 40 VALU ops,
// so 2 waves/SIMD still hides the L2 latency).
// Waves [0, nA/8)        : 8 rows each, streaming Bpack.
// Waves [nA/8, nA/8+nB/8): 8 cols each, streaming Apack.
// rowpack[i] = (xa0, xa1, a2, cert>thresh ? row_min_D : -1)
// colpack[j] = (xb0, xb1, b2, col_min_D)
#define MROWS 8
__global__ __launch_bounds__(256) void min_kernel(
    const float4* __restrict__ Apack, const float4* __restrict__ Bpack,
    float4* __restrict__ rowpack, float4* __restrict__ colpack,
    int nA, int nB) {
    int gwave = (int)((blockIdx.x * blockDim.x + threadIdx.x) >> 6);
    int lane = threadIdx.x & 63;
    int nRowWaves = nA / MROWS;
    float m[MROWS];
#pragma unroll
    for (int r = 0; r < MROWS; ++r) m[r] = 1e30f;
    if (gwave < nRowWaves) {
        int i0 = gwave * MROWS;
        float4 A[MROWS];
#pragma unroll
        for (int r = 0; r < MROWS; ++r) A[r] = Apack[i0 + r];
        for (int j = lane; j < nB; j += 64) {
            float4 b = Bpack[j];
#pragma unroll
            for (int r = 0; r < MROWS; ++r)
                m[r] = fminf(m[r], d2_exact(A[r].x, A[r].y, A[r].z, b.x, b.y, b.z));
        }
#pragma unroll
        for (int o = 32; o; o >>= 1) {
#pragma unroll
            for (int r = 0; r < MROWS; ++r)
                m[r] = fminf(m[r], __shfl_xor(m[r], o, 64));
        }
        if (lane == 0) {
#pragma unroll
            for (int r = 0; r < MROWS; ++r)
                rowpack[i0 + r] = make_float4(A[r].x, A[r].y, A[r].z,
                    (A[r].w > SAMPLE_THRESH) ? D_from_d2(m[r]) : -1.0f);
        }
    } else {
        int j0 = (gwave - nRowWaves) * MROWS;
        if (j0 >= nB) return;
        float4 B[MROWS];
#pragma unroll
        for (int r = 0; r < MROWS; ++r) B[r] = Bpack[j0 + r];
        for (int i = lane; i < nA; i += 64) {
            float4 a = Apack[i];
#pragma unroll
            for (int r = 0; r < MROWS; ++r)
                m[r] = fminf(m[r], d2_exact(a.x, a.y, a.z, B[r].x, B[r].y, B[r].z));
        }
#pragma unroll
        for (int o = 32; o; o >>= 1) {
#pragma unroll
            for (int r = 0; r < MROWS; ++r)
                m[r] = fminf(m[r], __shfl_xor(m[r], o, 64));
        }
        if (lane == 0) {
#pragma unroll
            for (int r = 0; r < MROWS; ++r)
                colpack[j0 + r] = make_float4(B[r].x, B[r].y, B[r].z, D_from_d2(m[r]));
        }
    }
}

// Kernel C: recompute D on the fly per 64x1024 tile (row/col packs in LDS),
// write where(mask, D, 0) with coalesced nontemporal float4 stores.
// Write-bound: 256 MB; nontemporal skips L2 allocate for the never-re-read stream.
#define TI 64
#define TJ 1024
__global__ __launch_bounds__(256) void out_kernel(
    const float4* __restrict__ rowpack, const float4* __restrict__ colpack,
    float* __restrict__ out, int N) {
    __shared__ float4 cp[TJ];
    __shared__ float4 rp[TI];
    int tid = threadIdx.x;
    int j0 = blockIdx.x * TJ;
    int i0 = blockIdx.y * TI;
    for (int k = tid; k < TJ; k += 256) cp[k] = colpack[j0 + k];
    if (tid < TI) rp[tid] = rowpack[i0 + tid];
    __syncthreads();
    float4 c0 = cp[tid * 4 + 0], c1 = cp[tid * 4 + 1];
    float4 c2 = cp[tid * 4 + 2], c3 = cp[tid * 4 + 3];
    size_t base = (size_t)i0 * (size_t)N + (size_t)j0 + (size_t)tid * 4;
    for (int r = 0; r < TI; ++r) {
        float4 a = rp[r];
        float d0 = D_from_d2(d2_exact(a.x, a.y, a.z, c0.x, c0.y, c0.z));
        float d1 = D_from_d2(d2_exact(a.x, a.y, a.z, c1.x, c1.y, c1.z));
        float d2 = D_from_d2(d2_exact(a.x, a.y, a.z, c2.x, c2.y, c2.z));
        float d3 = D_from_d2(d2_exact(a.x, a.y, a.z, c3.x, c3.y, c3.z));
        nfloat4 o;
        o.x = (d0 == a.w && d0 == c0.w) ? d0 : 0.0f;
        o.y = (d1 == a.w && d1 == c1.w) ? d1 : 0.0f;
        o.z = (d2 == a.w && d2 == c2.w) ? d2 : 0.0f;
        o.w = (d3 == a.w && d3 == c3.w) ? d3 : 0.0f;
        __builtin_nontemporal_store(o, (nfloat4*)(out + base + (size_t)r * (size_t)N));
    }
}

extern "C" void kernel_launch(void* const* d_in, const int* in_sizes, int n_in,
                              void* d_out, int out_size, void* d_ws, size_t ws_size,
                              hipStream_t stream) {
    const float* xA   = (const float*)d_in[0];
    const float* xB   = (const float*)d_in[1];
    const float* warp = (const float*)d_in[2];
    const float* cert = (const float*)d_in[3];
    int nA = in_sizes[0] / 2;   // 8192
    int nB = in_sizes[1] / 2;   // 8192
    const int H = 504, W = 1008;
    float* out = (float*)d_out;

    char* ws = (char*)d_ws;
    float4* Apack   = (float4*)ws;
    float4* Bpack   = Apack + nA;
    float4* rowpack = Bpack + nB;
    float4* colpack = rowpack + nA;

    int nmax = nA > nB ? nA : nB;
    sample_kernel<<<(nmax + 255) / 256, 256, 0, stream>>>(
        xA, xB, (const float4*)warp, cert, Apack, Bpack, nA, nB, H, W);

    int totWaves = nA / MROWS + nB / MROWS;
    min_kernel<<<(totWaves * 64 + 255) / 256, 256, 0, stream>>>(
        Apack, Bpack, rowpack, colpack, nA, nB);

    dim3 grid(nB / TJ, nA / TI);
    out_kernel<<<grid, 256, 0, stream>>>(rowpack, colpack, out, nB);
}